// Round 1
// baseline (197.926 us; speedup 1.0000x reference)
//
#include <hip/hip_runtime.h>
#include <math.h>

#define BATCH 256
#define DIN   5120
#define RANK  160
#define NS    16
#define NCAT  192   // RANK + NS + NS

// ---------------------------------------------------------------------------
// k1: [P | Bp | C] = x(256x5120) @ [W_delta(5120x160) | W_B(5120x16) | W_C(5120x16)]
// Split-K (20 chunks of 256), 64x64 block tile, 4x4 register tile/thread,
// atomicAdd into pre-zeroed ws buffers.
// ---------------------------------------------------------------------------
__global__ __launch_bounds__(256) void k1_gemm(
    const float* __restrict__ x, const float* __restrict__ Wd,
    const float* __restrict__ WB, const float* __restrict__ WC,
    float* __restrict__ P, float* __restrict__ Bp, float* __restrict__ Cc)
{
    __shared__ float xT[32][64];   // [k][m]
    __shared__ float Wt[32][64];   // [k][n]
    const int t  = threadIdx.x;
    const int m0 = blockIdx.x * 64;   // batch tile (4)
    const int n0 = blockIdx.y * 64;   // col tile (3)
    const int k0 = blockIdx.z * 256;  // k split (20)
    const int tm = (t >> 4) * 4;
    const int tn = (t & 15) * 4;

    const int lm  = t >> 2;        // x-stage: row
    const int lk  = (t & 3) * 8;   // x-stage: k offset
    const int ln  = t & 63;        // W-stage: col
    const int lkb = (t >> 6) * 8;  // W-stage: k offset

    // column -> source matrix mapping (uniform per thread, set once)
    const float* wsrc; int wstr;
    {
        const int c = n0 + ln;
        if (c < RANK)            { wsrc = Wd + c;                wstr = RANK; }
        else if (c < RANK + NS)  { wsrc = WB + (c - RANK);       wstr = NS;   }
        else                     { wsrc = WC + (c - RANK - NS);  wstr = NS;   }
    }

    float acc[4][4] = {{0.f}};

    for (int ks = 0; ks < 8; ++ks) {
        const int kb = k0 + ks * 32;
        {   // stage x tile (64m x 32k), transposed to [k][m]
            const float* src = x + (size_t)(m0 + lm) * DIN + kb + lk;
            const float4 a0 = *(const float4*)src;
            const float4 a1 = *(const float4*)(src + 4);
            xT[lk+0][lm]=a0.x; xT[lk+1][lm]=a0.y; xT[lk+2][lm]=a0.z; xT[lk+3][lm]=a0.w;
            xT[lk+4][lm]=a1.x; xT[lk+5][lm]=a1.y; xT[lk+6][lm]=a1.z; xT[lk+7][lm]=a1.w;
        }
        {   // stage W tile (32k x 64n)
            const float* wp = wsrc + (size_t)(kb + lkb) * wstr;
            #pragma unroll
            for (int i = 0; i < 8; ++i) { Wt[lkb + i][ln] = *wp; wp += wstr; }
        }
        __syncthreads();
        #pragma unroll
        for (int k = 0; k < 32; ++k) {
            const float4 a = *(const float4*)&xT[k][tm];
            const float4 b = *(const float4*)&Wt[k][tn];
            acc[0][0] += a.x*b.x; acc[0][1] += a.x*b.y; acc[0][2] += a.x*b.z; acc[0][3] += a.x*b.w;
            acc[1][0] += a.y*b.x; acc[1][1] += a.y*b.y; acc[1][2] += a.y*b.z; acc[1][3] += a.y*b.w;
            acc[2][0] += a.z*b.x; acc[2][1] += a.z*b.y; acc[2][2] += a.z*b.z; acc[2][3] += a.z*b.w;
            acc[3][0] += a.w*b.x; acc[3][1] += a.w*b.y; acc[3][2] += a.w*b.z; acc[3][3] += a.w*b.w;
        }
        __syncthreads();
    }

    #pragma unroll
    for (int i = 0; i < 4; ++i) {
        const int gm = m0 + tm + i;
        #pragma unroll
        for (int j = 0; j < 4; ++j) {
            const int c = n0 + tn + j;
            float* dst;
            if (c < RANK)           dst = P  + gm * RANK + c;
            else if (c < RANK + NS) dst = Bp + gm * NS + (c - RANK);
            else                    dst = Cc + gm * NS + (c - RANK - NS);
            atomicAdd(dst, acc[i][j]);
        }
    }
}

__device__ __forceinline__ float softplus20(float z)
{
    // matches jax.nn.softplus with linear region above 20
    if (z > 20.f) return z;
    return fmaxf(z, 0.f) + log1pf(__expf(-fabsf(z)));
}

// ---------------------------------------------------------------------------
// k2: dt(256x5120) = softplus(P(256x160) @ W_dt(160x5120) + b_dt)
// 64x64 tile, K=160 in 5 stages of 32, fused bias + softplus epilogue.
// ---------------------------------------------------------------------------
__global__ __launch_bounds__(256) void k2_gemm(
    const float* __restrict__ P, const float* __restrict__ Wdt,
    const float* __restrict__ bdt, float* __restrict__ dtb)
{
    __shared__ float aT[32][64];   // [k][m]
    __shared__ float Bt[32][64];   // [k][n]
    const int t  = threadIdx.x;
    const int m0 = blockIdx.x * 64;   // batch tile (4)
    const int n0 = blockIdx.y * 64;   // d tile (80)
    const int tm = (t >> 4) * 4;
    const int tn = (t & 15) * 4;

    const int lm  = t >> 2;
    const int lk  = (t & 3) * 8;
    const int ln  = t & 63;
    const int lkb = (t >> 6) * 8;

    float acc[4][4] = {{0.f}};

    for (int ks = 0; ks < 5; ++ks) {
        const int kb = ks * 32;
        {
            const float* src = P + (size_t)(m0 + lm) * RANK + kb + lk;
            const float4 a0 = *(const float4*)src;
            const float4 a1 = *(const float4*)(src + 4);
            aT[lk+0][lm]=a0.x; aT[lk+1][lm]=a0.y; aT[lk+2][lm]=a0.z; aT[lk+3][lm]=a0.w;
            aT[lk+4][lm]=a1.x; aT[lk+5][lm]=a1.y; aT[lk+6][lm]=a1.z; aT[lk+7][lm]=a1.w;
        }
        {
            const float* wp = Wdt + (size_t)(kb + lkb) * DIN + n0 + ln;
            #pragma unroll
            for (int i = 0; i < 8; ++i) { Bt[lkb + i][ln] = wp[(size_t)i * DIN]; }
        }
        __syncthreads();
        #pragma unroll
        for (int k = 0; k < 32; ++k) {
            const float4 a = *(const float4*)&aT[k][tm];
            const float4 b = *(const float4*)&Bt[k][tn];
            acc[0][0] += a.x*b.x; acc[0][1] += a.x*b.y; acc[0][2] += a.x*b.z; acc[0][3] += a.x*b.w;
            acc[1][0] += a.y*b.x; acc[1][1] += a.y*b.y; acc[1][2] += a.y*b.z; acc[1][3] += a.y*b.w;
            acc[2][0] += a.z*b.x; acc[2][1] += a.z*b.y; acc[2][2] += a.z*b.z; acc[2][3] += a.z*b.w;
            acc[3][0] += a.w*b.x; acc[3][1] += a.w*b.y; acc[3][2] += a.w*b.z; acc[3][3] += a.w*b.w;
        }
        __syncthreads();
    }

    const float4 bz = *(const float4*)&bdt[n0 + tn];
    #pragma unroll
    for (int i = 0; i < 4; ++i) {
        const int gm = m0 + tm + i;
        float4 o;
        o.x = softplus20(acc[i][0] + bz.x);
        o.y = softplus20(acc[i][1] + bz.y);
        o.z = softplus20(acc[i][2] + bz.z);
        o.w = softplus20(acc[i][3] + bz.w);
        *(float4*)&dtb[(size_t)gm * DIN + n0 + tn] = o;
    }
}

// ---------------------------------------------------------------------------
// k3: fused SSM update + readout. One thread per (b,d).
// y[b,d] = sum_n (exp(dt*(-exp(A_log[d,n])))*h[b,d,n] + dt*x*Bp[b,n]) * C[b,n]
//          + x[b,d]*D[d]
// ---------------------------------------------------------------------------
__global__ __launch_bounds__(256) void k3_ssm(
    const float* __restrict__ x, const float* __restrict__ h,
    const float* __restrict__ A_log, const float* __restrict__ dtb,
    const float* __restrict__ Bp, const float* __restrict__ Cc,
    const float* __restrict__ Dv, float* __restrict__ y)
{
    __shared__ float sB[NS], sC[NS];
    const int b = blockIdx.x / 20;
    const int d = (blockIdx.x % 20) * 256 + threadIdx.x;
    if (threadIdx.x < NS)            sB[threadIdx.x]      = Bp[b * NS + threadIdx.x];
    else if (threadIdx.x < 2 * NS)   sC[threadIdx.x - NS] = Cc[b * NS + threadIdx.x - NS];
    __syncthreads();

    const float dtv = dtb[(size_t)b * DIN + d];
    const float xv  = x[(size_t)b * DIN + d];
    const float dtx = dtv * xv;
    const float4* hp = (const float4*)(h + ((size_t)b * DIN + d) * NS);
    const float4* ap = (const float4*)(A_log + (size_t)d * NS);

    float acc = 0.f;
    #pragma unroll
    for (int q = 0; q < 4; ++q) {
        const float4 h4 = hp[q];
        const float4 a4 = ap[q];
        const float ab0 = __expf(dtv * -__expf(a4.x));
        const float ab1 = __expf(dtv * -__expf(a4.y));
        const float ab2 = __expf(dtv * -__expf(a4.z));
        const float ab3 = __expf(dtv * -__expf(a4.w));
        acc += (ab0 * h4.x + dtx * sB[4*q+0]) * sC[4*q+0];
        acc += (ab1 * h4.y + dtx * sB[4*q+1]) * sC[4*q+1];
        acc += (ab2 * h4.z + dtx * sB[4*q+2]) * sC[4*q+2];
        acc += (ab3 * h4.w + dtx * sB[4*q+3]) * sC[4*q+3];
    }
    y[(size_t)b * DIN + d] = acc + xv * Dv[d];
}

// ---------------------------------------------------------------------------
extern "C" void kernel_launch(void* const* d_in, const int* in_sizes, int n_in,
                              void* d_out, int out_size, void* d_ws, size_t ws_size,
                              hipStream_t stream)
{
    const float* x     = (const float*)d_in[0];
    const float* h     = (const float*)d_in[1];
    const float* Wd    = (const float*)d_in[2];
    const float* Wdt   = (const float*)d_in[3];
    const float* bdt   = (const float*)d_in[4];
    const float* A_log = (const float*)d_in[5];
    const float* WB    = (const float*)d_in[6];
    const float* WC    = (const float*)d_in[7];
    const float* Dv    = (const float*)d_in[8];
    float* out = (float*)d_out;

    // ws layout (floats): P (256x160) | Bp (256x16) | C (256x16) | dt (256x5120)
    float* ws  = (float*)d_ws;
    float* P   = ws;
    float* Bp  = ws + BATCH * RANK;
    float* Cc  = Bp + BATCH * NS;
    float* dtb = Cc + BATCH * NS;

    // zero the atomic accumulation targets (P/Bp/C = 49152 floats)
    hipMemsetAsync(ws, 0, (size_t)BATCH * NCAT * sizeof(float), stream);

    k1_gemm<<<dim3(4, 3, 20), 256, 0, stream>>>(x, Wd, WB, WC, P, Bp, Cc);
    k2_gemm<<<dim3(4, 80),    256, 0, stream>>>(P, Wdt, bdt, dtb);
    k3_ssm <<<dim3(BATCH * 20), 256, 0, stream>>>(x, h, A_log, dtb, Bp, Cc, Dv, out);
}

// Round 2
// 190.133 us; speedup vs baseline: 1.0410x; 1.0410x over previous
//
#include <hip/hip_runtime.h>
#include <math.h>

#define BATCH 256
#define DIN   5120
#define RANK  160
#define NS    16
#define NCAT  192   // RANK + NS + NS

// ---------------------------------------------------------------------------
// k1: [P | Bp | C] = x(256x5120) @ [W_delta(5120x160) | W_B(5120x16) | W_C(5120x16)]
// Split-K (20 chunks of 256), 64x64 block tile, 4x4 register tile/thread,
// atomicAdd into pre-zeroed ws buffers.
// ---------------------------------------------------------------------------
__global__ __launch_bounds__(256) void k1_gemm(
    const float* __restrict__ x, const float* __restrict__ Wd,
    const float* __restrict__ WB, const float* __restrict__ WC,
    float* __restrict__ P, float* __restrict__ Bp, float* __restrict__ Cc)
{
    __shared__ float xT[32][64];   // [k][m]
    __shared__ float Wt[32][64];   // [k][n]
    const int t  = threadIdx.x;
    const int m0 = blockIdx.x * 64;   // batch tile (4)
    const int n0 = blockIdx.y * 64;   // col tile (3)
    const int k0 = blockIdx.z * 256;  // k split (20)
    const int tm = (t >> 4) * 4;
    const int tn = (t & 15) * 4;

    const int lm  = t >> 2;        // x-stage: row
    const int lk  = (t & 3) * 8;   // x-stage: k offset
    const int ln  = t & 63;        // W-stage: col
    const int lkb = (t >> 6) * 8;  // W-stage: k offset

    // column -> source matrix mapping (uniform per thread, set once)
    const float* wsrc; int wstr;
    {
        const int c = n0 + ln;
        if (c < RANK)            { wsrc = Wd + c;                wstr = RANK; }
        else if (c < RANK + NS)  { wsrc = WB + (c - RANK);       wstr = NS;   }
        else                     { wsrc = WC + (c - RANK - NS);  wstr = NS;   }
    }

    float acc[4][4] = {{0.f}};

    for (int ks = 0; ks < 8; ++ks) {
        const int kb = k0 + ks * 32;
        {   // stage x tile (64m x 32k), transposed to [k][m]
            const float* src = x + (size_t)(m0 + lm) * DIN + kb + lk;
            const float4 a0 = *(const float4*)src;
            const float4 a1 = *(const float4*)(src + 4);
            xT[lk+0][lm]=a0.x; xT[lk+1][lm]=a0.y; xT[lk+2][lm]=a0.z; xT[lk+3][lm]=a0.w;
            xT[lk+4][lm]=a1.x; xT[lk+5][lm]=a1.y; xT[lk+6][lm]=a1.z; xT[lk+7][lm]=a1.w;
        }
        {   // stage W tile (32k x 64n)
            const float* wp = wsrc + (size_t)(kb + lkb) * wstr;
            #pragma unroll
            for (int i = 0; i < 8; ++i) { Wt[lkb + i][ln] = *wp; wp += wstr; }
        }
        __syncthreads();
        #pragma unroll
        for (int k = 0; k < 32; ++k) {
            const float4 a = *(const float4*)&xT[k][tm];
            const float4 b = *(const float4*)&Wt[k][tn];
            acc[0][0] += a.x*b.x; acc[0][1] += a.x*b.y; acc[0][2] += a.x*b.z; acc[0][3] += a.x*b.w;
            acc[1][0] += a.y*b.x; acc[1][1] += a.y*b.y; acc[1][2] += a.y*b.z; acc[1][3] += a.y*b.w;
            acc[2][0] += a.z*b.x; acc[2][1] += a.z*b.y; acc[2][2] += a.z*b.z; acc[2][3] += a.z*b.w;
            acc[3][0] += a.w*b.x; acc[3][1] += a.w*b.y; acc[3][2] += a.w*b.z; acc[3][3] += a.w*b.w;
        }
        __syncthreads();
    }

    #pragma unroll
    for (int i = 0; i < 4; ++i) {
        const int gm = m0 + tm + i;
        #pragma unroll
        for (int j = 0; j < 4; ++j) {
            const int c = n0 + tn + j;
            float* dst;
            if (c < RANK)           dst = P  + gm * RANK + c;
            else if (c < RANK + NS) dst = Bp + gm * NS + (c - RANK);
            else                    dst = Cc + gm * NS + (c - RANK - NS);
            atomicAdd(dst, acc[i][j]);
        }
    }
}

__device__ __forceinline__ float softplus20(float z)
{
    if (z > 20.f) return z;
    return fmaxf(z, 0.f) + log1pf(__expf(-fabsf(z)));
}

// ---------------------------------------------------------------------------
// k2: fused dt-GEMM + SSM update + readout.
// Block = 4 batches x 256 d-channels. dt computed in-register from
// P (LDS, broadcast) x Wdt columns (coalesced, L2-resident).
// A' = -exp(A_log[d,:]) computed once per d, reused across the 4 batches.
// ---------------------------------------------------------------------------
__global__ __launch_bounds__(256) void k2_fused(
    const float* __restrict__ P, const float* __restrict__ Wdt,
    const float* __restrict__ bdt, const float* __restrict__ x,
    const float* __restrict__ h, const float* __restrict__ A_log,
    const float* __restrict__ Bp, const float* __restrict__ Cc,
    const float* __restrict__ Dv, float* __restrict__ y)
{
    __shared__ float sP[4][RANK];   // P rows for 4 batches
    __shared__ float sB[4][NS];
    __shared__ float sC[4][NS];

    const int tid = threadIdx.x;
    const int d   = blockIdx.x * 256 + tid;   // 20 tiles
    const int b0  = blockIdx.y * 4;           // 64 quads

    // stage P rows (contiguous 640 floats) and Bp/C rows (64 floats each)
    #pragma unroll
    for (int i = tid; i < 4 * RANK; i += 256)
        sP[i / RANK][i % RANK] = P[(size_t)b0 * RANK + i];
    if (tid < 64)                    sB[tid >> 4][tid & 15] = Bp[b0 * NS + tid];
    else if (tid < 128) { int u = tid - 64; sC[u >> 4][u & 15] = Cc[b0 * NS + u]; }
    __syncthreads();

    // dt for 4 batches: dot(P[b,:], Wdt[:,d]) over K=160
    float acc0 = 0.f, acc1 = 0.f, acc2 = 0.f, acc3 = 0.f;
    const float* wcol = Wdt + d;
    #pragma unroll 8
    for (int k = 0; k < RANK; ++k) {
        const float w = wcol[(size_t)k * DIN];
        acc0 += sP[0][k] * w;
        acc1 += sP[1][k] * w;
        acc2 += sP[2][k] * w;
        acc3 += sP[3][k] * w;
    }
    const float bb = bdt[d];
    float dt[4];
    dt[0] = softplus20(acc0 + bb);
    dt[1] = softplus20(acc1 + bb);
    dt[2] = softplus20(acc2 + bb);
    dt[3] = softplus20(acc3 + bb);

    // A' = -exp(A_log[d,:]) once per d
    float A2[NS];
    {
        const float4* ap = (const float4*)(A_log + (size_t)d * NS);
        #pragma unroll
        for (int q = 0; q < 4; ++q) {
            const float4 a4 = ap[q];
            A2[4*q+0] = -__expf(a4.x);
            A2[4*q+1] = -__expf(a4.y);
            A2[4*q+2] = -__expf(a4.z);
            A2[4*q+3] = -__expf(a4.w);
        }
    }
    const float dv = Dv[d];

    #pragma unroll
    for (int b = 0; b < 4; ++b) {
        const int gb = b0 + b;
        const float dtv = dt[b];
        const float xv  = x[(size_t)gb * DIN + d];
        const float dtx = dtv * xv;
        const float4* hp = (const float4*)(h + ((size_t)gb * DIN + d) * NS);
        float acc = 0.f;
        #pragma unroll
        for (int q = 0; q < 4; ++q) {
            const float4 h4 = hp[q];
            acc += (__expf(dtv * A2[4*q+0]) * h4.x + dtx * sB[b][4*q+0]) * sC[b][4*q+0];
            acc += (__expf(dtv * A2[4*q+1]) * h4.y + dtx * sB[b][4*q+1]) * sC[b][4*q+1];
            acc += (__expf(dtv * A2[4*q+2]) * h4.z + dtx * sB[b][4*q+2]) * sC[b][4*q+2];
            acc += (__expf(dtv * A2[4*q+3]) * h4.w + dtx * sB[b][4*q+3]) * sC[b][4*q+3];
        }
        y[(size_t)gb * DIN + d] = acc + xv * dv;
    }
}

// ---------------------------------------------------------------------------
extern "C" void kernel_launch(void* const* d_in, const int* in_sizes, int n_in,
                              void* d_out, int out_size, void* d_ws, size_t ws_size,
                              hipStream_t stream)
{
    const float* x     = (const float*)d_in[0];
    const float* h     = (const float*)d_in[1];
    const float* Wd    = (const float*)d_in[2];
    const float* Wdt   = (const float*)d_in[3];
    const float* bdt   = (const float*)d_in[4];
    const float* A_log = (const float*)d_in[5];
    const float* WB    = (const float*)d_in[6];
    const float* WC    = (const float*)d_in[7];
    const float* Dv    = (const float*)d_in[8];
    float* out = (float*)d_out;

    // ws layout (floats): P (256x160) | Bp (256x16) | C (256x16)
    float* ws  = (float*)d_ws;
    float* P   = ws;
    float* Bp  = ws + BATCH * RANK;
    float* Cc  = Bp + BATCH * NS;

    hipMemsetAsync(ws, 0, (size_t)BATCH * NCAT * sizeof(float), stream);

    k1_gemm <<<dim3(4, 3, 20), 256, 0, stream>>>(x, Wd, WB, WC, P, Bp, Cc);
    k2_fused<<<dim3(20, 64),   256, 0, stream>>>(P, Wdt, bdt, x, h, A_log, Bp, Cc, Dv, out);
}